// Round 13
// baseline (137.424 us; speedup 1.0000x reference)
//
#include <hip/hip_runtime.h>
#include <hip/hip_bf16.h>

#define GN 50000
#define GE 800000
#define GD 96
#define GC 40
#define L2EPS 1e-12f

typedef __attribute__((ext_vector_type(8))) short short8v;   // 8 bf16 = 4 VGPR
typedef __attribute__((ext_vector_type(4))) float f32x4;

__device__ __forceinline__ unsigned f2bf(float x) {           // RNE float->bf16 bits
    union { float f; unsigned u; } v; v.f = x;
    return (v.u + 0x7fffu + ((v.u >> 16) & 1u)) >> 16;
}
__device__ __forceinline__ float bflo(unsigned u) { return __uint_as_float(u << 16); }
__device__ __forceinline__ float bfhi(unsigned u) { return __uint_as_float(u & 0xffff0000u); }

__device__ __forceinline__ int lbound(const int* __restrict__ row, int key) {
    int lo = 0, hi = GE;
    while (lo < hi) {
        int mid = (lo + hi) >> 1;
        if (row[mid] < key) lo = mid + 1; else hi = mid;
    }
    return lo;
}

// prep: rp[i]=lower_bound(row,i) ; Wb1/Wb2 = MFMA B-fragment packs of w1/w2.
__global__ void prep_k(const int* __restrict__ row, const float* __restrict__ w1,
                       const float* __restrict__ w2, int* __restrict__ rp,
                       unsigned* __restrict__ Wb1, unsigned* __restrict__ Wb2) {
    int i = blockIdx.x * blockDim.x + threadIdx.x;
    if (i <= GN) rp[i] = lbound(row, i);
    if (i < 2 * 4608) {
        const float* W = (i < 4608) ? w1 : w2;
        unsigned* Wb   = (i < 4608) ? Wb1 : Wb2;
        int j = (i < 4608) ? i : i - 4608;
        int r = j & 3;
        int lane = (j >> 2) & 63;
        int frag = j >> 8;                 // 0..17
        int nt = frag / 3, kt = frag - nt * 3;
        int c = nt * 16 + (lane & 15);
        int k = kt * 32 + (lane >> 4) * 8 + r * 2;
        Wb[j] = f2bf(W[k * GD + c]) | (f2bf(W[(k + 1) * GD + c]) << 16);
    }
}

// O = A @ W, bf16 out, SPLIT into two half-tables:
// lo = O[0 .. GN*48) = cols 0..47 ; hi = O[GN*48 ..) = cols 48..95. 48 bf16/row each.
__global__ __launch_bounds__(64) void gemm_mfma_k(const float* __restrict__ A,
                                                  const uint4* __restrict__ Wb,
                                                  unsigned short* __restrict__ O) {
    const int tile = blockIdx.x;            // 0..3124
    const int l  = threadIdx.x;
    const int m  = l & 15;
    const int kg = l >> 4;

    const float* arow = A + (size_t)(tile * 16 + m) * GD + kg * 8;
    short8v ah[3], al[3];
#pragma unroll
    for (int kt = 0; kt < 3; ++kt) {
        const float4* ap = reinterpret_cast<const float4*>(arow + kt * 32);
        float4 x0 = ap[0], x1 = ap[1];
        uint4 H, L;
        H.x = f2bf(x0.x) | (f2bf(x0.y) << 16);
        H.y = f2bf(x0.z) | (f2bf(x0.w) << 16);
        H.z = f2bf(x1.x) | (f2bf(x1.y) << 16);
        H.w = f2bf(x1.z) | (f2bf(x1.w) << 16);
        L.x = f2bf(x0.x - bflo(H.x)) | (f2bf(x0.y - bfhi(H.x)) << 16);
        L.y = f2bf(x0.z - bflo(H.y)) | (f2bf(x0.w - bfhi(H.y)) << 16);
        L.z = f2bf(x1.x - bflo(H.z)) | (f2bf(x1.y - bfhi(H.z)) << 16);
        L.w = f2bf(x1.z - bflo(H.w)) | (f2bf(x1.w - bfhi(H.w)) << 16);
        union { uint4 u; short8v s; } ch, cl;
        ch.u = H; cl.u = L;
        ah[kt] = ch.s; al[kt] = cl.s;
    }

#pragma unroll
    for (int nt = 0; nt < 6; ++nt) {
        f32x4 acc = {0.f, 0.f, 0.f, 0.f};
#pragma unroll
        for (int kt = 0; kt < 3; ++kt) {
            union { uint4 u; short8v s; } b;
            b.u = Wb[(nt * 3 + kt) * 64 + l];
            acc = __builtin_amdgcn_mfma_f32_16x16x32_bf16(ah[kt], b.s, acc, 0, 0, 0);
            acc = __builtin_amdgcn_mfma_f32_16x16x32_bf16(al[kt], b.s, acc, 0, 0, 0);
        }
        unsigned short* dst = O + ((nt < 3) ? 0 : (size_t)GN * 48);
        int ccol = (nt % 3) * 16 + m;     // 0..47 within the half-table
#pragma unroll
        for (int reg = 0; reg < 4; ++reg) {
            int rrow = tile * 16 + kg * 4 + reg;
            dst[(size_t)rrow * 48 + ccol] = (unsigned short)f2bf(acc[reg]);
        }
    }
}

#define FMA4(U, V)                                                    \
    a0 += (V) * bflo((U).x); a1 += (V) * bfhi((U).x);                 \
    a2 += (V) * bflo((U).y); a3 += (V) * bfhi((U).y);

// half-table SpMM: Tb = 48-col bf16 table (24 uints/row, 4.8 MB ~ per-XCD L2).
// 12 lanes/node, lane t owns cols colOff+t*4 .. +3 (one uint2 per edge). relu out.
__global__ void spmm_half_k(const int* __restrict__ rp, const int* __restrict__ col,
                            const float* __restrict__ vals,
                            const unsigned* __restrict__ Tb, float* __restrict__ H,
                            int colOff) {
    int idx = blockIdx.x * blockDim.x + threadIdx.x;
    int n = idx / 12;
    if (n >= GN) return;
    int t = idx - n * 12;
    int e0 = rp[n], e1 = rp[n + 1];
    float a0=0,a1=0,a2=0,a3=0;
    int e = e0;
    for (; e + 4 <= e1; e += 4) {
        int c0 = col[e], c1 = col[e+1], c2 = col[e+2], c3 = col[e+3];
        float v0 = vals[e], v1 = vals[e+1], v2 = vals[e+2], v3 = vals[e+3];
        uint2 u0 = *reinterpret_cast<const uint2*>(Tb + (size_t)c0 * 24 + t * 2);
        uint2 u1 = *reinterpret_cast<const uint2*>(Tb + (size_t)c1 * 24 + t * 2);
        uint2 u2 = *reinterpret_cast<const uint2*>(Tb + (size_t)c2 * 24 + t * 2);
        uint2 u3 = *reinterpret_cast<const uint2*>(Tb + (size_t)c3 * 24 + t * 2);
        FMA4(u0, v0) FMA4(u1, v1) FMA4(u2, v2) FMA4(u3, v3)
    }
    for (; e < e1; ++e) {
        float v = vals[e];
        uint2 u = *reinterpret_cast<const uint2*>(Tb + (size_t)col[e] * 24 + t * 2);
        FMA4(u, v)
    }
    *reinterpret_cast<float4*>(H + (size_t)n * GD + colOff + t * 4) =
        make_float4(fmaxf(a0,0.f), fmaxf(a1,0.f), fmaxf(a2,0.f), fmaxf(a3,0.f));
}

// fused l2-normalize (in place on A) + classifier + softmax.
// 320 threads = 32 row-quads x 10 col-quad threads; logits via LDS; softmax 1 thr/row.
__global__ __launch_bounds__(320) void cls_sm_k(float* __restrict__ A,
                                                const float* __restrict__ WC,
                                                const float* __restrict__ BC,
                                                float* __restrict__ PROBS) {
    __shared__ float4 w4[GD * 10];         // 15360 B
    __shared__ float lg[128][GC];          // 20480 B
    const float4* W4 = reinterpret_cast<const float4*>(WC);
    for (int i = threadIdx.x; i < GD * 10; i += 320) w4[i] = W4[i];
    __syncthreads();

    const int tid = threadIdx.x;
    const int lq = tid / 10;               // 0..31 local row-quad
    const int q  = tid - lq * 10;          // 0..9 col-quad
    const int r0 = (blockIdx.x * 32 + lq) * 4;
    if (r0 < GN) {
        float4* a4 = reinterpret_cast<float4*>(A + (size_t)r0 * GD);  // 4 rows x 24 f4
        // pass A: sum-of-squares per row (redundant across the 10 threads, identical order)
        float ss0=0.f, ss1=0.f, ss2=0.f, ss3=0.f;
#pragma unroll 6
        for (int i = 0; i < 24; ++i) {
            float4 v0 = a4[i], v1 = a4[24+i], v2 = a4[48+i], v3 = a4[72+i];
            ss0 += v0.x*v0.x + v0.y*v0.y + v0.z*v0.z + v0.w*v0.w;
            ss1 += v1.x*v1.x + v1.y*v1.y + v1.z*v1.z + v1.w*v1.w;
            ss2 += v2.x*v2.x + v2.y*v2.y + v2.z*v2.z + v2.w*v2.w;
            ss3 += v3.x*v3.x + v3.y*v3.y + v3.z*v3.z + v3.w*v3.w;
        }
        float s0 = rsqrtf(fmaxf(ss0, L2EPS));
        float s1 = rsqrtf(fmaxf(ss1, L2EPS));
        float s2 = rsqrtf(fmaxf(ss2, L2EPS));
        float s3 = rsqrtf(fmaxf(ss3, L2EPS));

        // pass B: logits on raw values (scale folded in at the end) + distributed
        // in-place write-back of the normalized rows (i%10==q -> this thread writes).
        float4 acc0 = {0,0,0,0}, acc1 = {0,0,0,0}, acc2 = {0,0,0,0}, acc3 = {0,0,0,0};
        for (int i = 0; i < 24; ++i) {
            float4 a0 = a4[i], a1 = a4[24+i], a2 = a4[48+i], a3 = a4[72+i];
            if (i % 10 == q) {
                a4[i]    = make_float4(a0.x*s0, a0.y*s0, a0.z*s0, a0.w*s0);
                a4[24+i] = make_float4(a1.x*s1, a1.y*s1, a1.z*s1, a1.w*s1);
                a4[48+i] = make_float4(a2.x*s2, a2.y*s2, a2.z*s2, a2.w*s2);
                a4[72+i] = make_float4(a3.x*s3, a3.y*s3, a3.z*s3, a3.w*s3);
            }
#pragma unroll
            for (int kk = 0; kk < 4; ++kk) {
                float4 w = w4[(i * 4 + kk) * 10 + q];
                float t0 = ((const float*)&a0)[kk];
                float t1 = ((const float*)&a1)[kk];
                float t2 = ((const float*)&a2)[kk];
                float t3 = ((const float*)&a3)[kk];
                acc0.x += t0 * w.x; acc0.y += t0 * w.y; acc0.z += t0 * w.z; acc0.w += t0 * w.w;
                acc1.x += t1 * w.x; acc1.y += t1 * w.y; acc1.z += t1 * w.z; acc1.w += t1 * w.w;
                acc2.x += t2 * w.x; acc2.y += t2 * w.y; acc2.z += t2 * w.z; acc2.w += t2 * w.w;
                acc3.x += t3 * w.x; acc3.y += t3 * w.y; acc3.z += t3 * w.z; acc3.w += t3 * w.w;
            }
        }
        float4 b = *reinterpret_cast<const float4*>(BC + q * 4);
        acc0.x = acc0.x*s0 + b.x; acc0.y = acc0.y*s0 + b.y; acc0.z = acc0.z*s0 + b.z; acc0.w = acc0.w*s0 + b.w;
        acc1.x = acc1.x*s1 + b.x; acc1.y = acc1.y*s1 + b.y; acc1.z = acc1.z*s1 + b.z; acc1.w = acc1.w*s1 + b.w;
        acc2.x = acc2.x*s2 + b.x; acc2.y = acc2.y*s2 + b.y; acc2.z = acc2.z*s2 + b.z; acc2.w = acc2.w*s2 + b.w;
        acc3.x = acc3.x*s3 + b.x; acc3.y = acc3.y*s3 + b.y; acc3.z = acc3.z*s3 + b.z; acc3.w = acc3.w*s3 + b.w;
        *reinterpret_cast<float4*>(&lg[lq * 4 + 0][q * 4]) = acc0;
        *reinterpret_cast<float4*>(&lg[lq * 4 + 1][q * 4]) = acc1;
        *reinterpret_cast<float4*>(&lg[lq * 4 + 2][q * 4]) = acc2;
        *reinterpret_cast<float4*>(&lg[lq * 4 + 3][q * 4]) = acc3;
    }
    __syncthreads();

    if (tid < 128) {
        int r = blockIdx.x * 128 + tid;
        if (r < GN) {
            const float* row = lg[tid];
            float m = row[0];
#pragma unroll
            for (int c = 1; c < GC; ++c) m = fmaxf(m, row[c]);
            float ex[GC];
            float sum = 0.f;
#pragma unroll
            for (int c = 0; c < GC; ++c) { ex[c] = __expf(row[c] - m); sum += ex[c]; }
            float inv = 1.f / sum;
            float4* pr = reinterpret_cast<float4*>(PROBS + (size_t)r * GC);
#pragma unroll
            for (int i = 0; i < 10; ++i)
                pr[i] = make_float4(ex[i*4] * inv, ex[i*4+1] * inv,
                                    ex[i*4+2] * inv, ex[i*4+3] * inv);
        }
    }
}

extern "C" void kernel_launch(void* const* d_in, const int* in_sizes, int n_in,
                              void* d_out, int out_size, void* d_ws, size_t ws_size,
                              hipStream_t stream) {
    const int*   row  = (const int*)d_in[0];
    const int*   col  = (const int*)d_in[1];
    const float* vals = (const float*)d_in[2];
    const float* x    = (const float*)d_in[3];
    const float* w1   = (const float*)d_in[4];
    const float* w2   = (const float*)d_in[5];
    const float* wc   = (const float*)d_in[6];
    const float* bc   = (const float*)d_in[7];

    float* out   = (float*)d_out;                 // [N, D]
    float* probs = out + (size_t)GN * GD;         // [N, C]

    char*  ws  = (char*)d_ws;
    int*   rp  = (int*)ws;                                        // (N+1) ints
    size_t off = (((size_t)(GN + 1) * 4) + 511) & ~(size_t)511;
    unsigned short* tb = (unsigned short*)(ws + off);  // two bf16 half-tables, GN*48 each
    off += (size_t)GN * GD * 2;                        // 9.6 MB total
    off = (off + 511) & ~(size_t)511;
    unsigned* Wb1 = (unsigned*)(ws + off);        // 4608 uints MFMA B-frags of w1
    unsigned* Wb2 = Wb1 + 4608;

    const unsigned* tlo = (const unsigned*)tb;
    const unsigned* thi = (const unsigned*)(tb + (size_t)GN * 48);
    const int spmm_blocks = (GN * 12 + 255) / 256;

    // rp + W packs
    prep_k<<<(GN + 1 + 255) / 256, 256, 0, stream>>>(row, w1, w2, rp, Wb1, Wb2);
    // t1 = bf16(x @ w1), split half-tables
    gemm_mfma_k<<<GN / 16, 64, 0, stream>>>(x, (const uint4*)Wb1, tb);
    // h1 = relu(A @ t1) -> d_out, two L2-resident passes
    spmm_half_k<<<spmm_blocks, 256, 0, stream>>>(rp, col, vals, tlo, out, 0);
    spmm_half_k<<<spmm_blocks, 256, 0, stream>>>(rp, col, vals, thi, out, 48);
    // t2 = bf16(h1 @ w2), split half-tables
    gemm_mfma_k<<<GN / 16, 64, 0, stream>>>(out, (const uint4*)Wb2, tb);
    // h2raw = relu(A @ t2) -> d_out
    spmm_half_k<<<spmm_blocks, 256, 0, stream>>>(rp, col, vals, tlo, out, 0);
    spmm_half_k<<<spmm_blocks, 256, 0, stream>>>(rp, col, vals, thi, out, 48);
    // out = l2norm(h2raw) in place ; probs = softmax(out @ wc + bc)
    cls_sm_k<<<(GN + 127) / 128, 320, 0, stream>>>(out, wc, bc, probs);
}

// Round 15
// 114.914 us; speedup vs baseline: 1.1959x; 1.1959x over previous
//
#include <hip/hip_runtime.h>
#include <hip/hip_bf16.h>

#define GN 50000
#define GE 800000
#define GD 96
#define GC 40
#define L2EPS 1e-12f

typedef __attribute__((ext_vector_type(8))) short short8v;   // 8 bf16 = 4 VGPR
typedef __attribute__((ext_vector_type(4))) float f32x4;

__device__ __forceinline__ unsigned f2bf(float x) {           // RNE float->bf16 bits
    union { float f; unsigned u; } v; v.f = x;
    return (v.u + 0x7fffu + ((v.u >> 16) & 1u)) >> 16;
}
__device__ __forceinline__ float bflo(unsigned u) { return __uint_as_float(u << 16); }
__device__ __forceinline__ float bfhi(unsigned u) { return __uint_as_float(u & 0xffff0000u); }

__device__ __forceinline__ void nt_store4(float* p, float x, float y, float z, float w) {
    f32x4 v = {x, y, z, w};
    __builtin_nontemporal_store(v, reinterpret_cast<f32x4*>(p));
}

__device__ __forceinline__ int lbound(const int* __restrict__ row, int key) {
    int lo = 0, hi = GE;
    while (lo < hi) {
        int mid = (lo + hi) >> 1;
        if (row[mid] < key) lo = mid + 1; else hi = mid;
    }
    return lo;
}

// prep: rp[i]=lower_bound(row,i) ; Wb1/Wb2 = MFMA B-fragment packs of w1/w2.
__global__ void prep_k(const int* __restrict__ row, const float* __restrict__ w1,
                       const float* __restrict__ w2, int* __restrict__ rp,
                       unsigned* __restrict__ Wb1, unsigned* __restrict__ Wb2) {
    int i = blockIdx.x * blockDim.x + threadIdx.x;
    if (i <= GN) rp[i] = lbound(row, i);
    if (i < 2 * 4608) {
        const float* W = (i < 4608) ? w1 : w2;
        unsigned* Wb   = (i < 4608) ? Wb1 : Wb2;
        int j = (i < 4608) ? i : i - 4608;
        int r = j & 3;
        int lane = (j >> 2) & 63;
        int frag = j >> 8;                 // 0..17
        int nt = frag / 3, kt = frag - nt * 3;
        int c = nt * 16 + (lane & 15);
        int k = kt * 32 + (lane >> 4) * 8 + r * 2;
        Wb[j] = f2bf(W[k * GD + c]) | (f2bf(W[(k + 1) * GD + c]) << 16);
    }
}

// O_bf16[N,96] = A_f32[N,96] @ W ; MFMA 16x16x32 bf16 with split-A (hi+lo -> A exact).
__global__ __launch_bounds__(64) void gemm_mfma_k(const float* __restrict__ A,
                                                  const uint4* __restrict__ Wb,
                                                  unsigned short* __restrict__ O) {
    const int tile = blockIdx.x;            // 0..3124
    const int l  = threadIdx.x;
    const int m  = l & 15;
    const int kg = l >> 4;

    const float* arow = A + (size_t)(tile * 16 + m) * GD + kg * 8;
    short8v ah[3], al[3];
#pragma unroll
    for (int kt = 0; kt < 3; ++kt) {
        const float4* ap = reinterpret_cast<const float4*>(arow + kt * 32);
        float4 x0 = ap[0], x1 = ap[1];
        uint4 H, L;
        H.x = f2bf(x0.x) | (f2bf(x0.y) << 16);
        H.y = f2bf(x0.z) | (f2bf(x0.w) << 16);
        H.z = f2bf(x1.x) | (f2bf(x1.y) << 16);
        H.w = f2bf(x1.z) | (f2bf(x1.w) << 16);
        L.x = f2bf(x0.x - bflo(H.x)) | (f2bf(x0.y - bfhi(H.x)) << 16);
        L.y = f2bf(x0.z - bflo(H.y)) | (f2bf(x0.w - bfhi(H.y)) << 16);
        L.z = f2bf(x1.x - bflo(H.z)) | (f2bf(x1.y - bfhi(H.z)) << 16);
        L.w = f2bf(x1.z - bflo(H.w)) | (f2bf(x1.w - bfhi(H.w)) << 16);
        union { uint4 u; short8v s; } ch, cl;
        ch.u = H; cl.u = L;
        ah[kt] = ch.s; al[kt] = cl.s;
    }

#pragma unroll
    for (int nt = 0; nt < 6; ++nt) {
        f32x4 acc = {0.f, 0.f, 0.f, 0.f};
#pragma unroll
        for (int kt = 0; kt < 3; ++kt) {
            union { uint4 u; short8v s; } b;
            b.u = Wb[(nt * 3 + kt) * 64 + l];
            acc = __builtin_amdgcn_mfma_f32_16x16x32_bf16(ah[kt], b.s, acc, 0, 0, 0);
            acc = __builtin_amdgcn_mfma_f32_16x16x32_bf16(al[kt], b.s, acc, 0, 0, 0);
        }
        int ccol = nt * 16 + m;
#pragma unroll
        for (int reg = 0; reg < 4; ++reg) {
            int rrow = tile * 16 + kg * 4 + reg;
            O[(size_t)rrow * GD + ccol] = (unsigned short)f2bf(acc[reg]);
        }
    }
}

#define FMA8(U, V)                                                    \
    a0 += (V) * bflo((U).x); a1 += (V) * bfhi((U).x);                 \
    a2 += (V) * bflo((U).y); a3 += (V) * bfhi((U).y);                 \
    a4 += (V) * bflo((U).z); a5 += (V) * bfhi((U).z);                 \
    a6 += (V) * bflo((U).w); a7 += (V) * bfhi((U).w);

// 12 threads/node; lane t gathers one uint4 (cols t*8..t*8+7) per edge; unroll-4.
// col/vals: nontemporal (single-use streams — keep L2 for the gather table).
__global__ void spmm_relu_k(const int* __restrict__ rp, const int* __restrict__ col,
                            const float* __restrict__ vals,
                            const unsigned* __restrict__ Tb, float* __restrict__ H) {
    int idx = blockIdx.x * blockDim.x + threadIdx.x;
    int n = idx / 12;
    if (n >= GN) return;
    int t = idx - n * 12;
    int e0 = rp[n], e1 = rp[n + 1];
    float a0=0,a1=0,a2=0,a3=0,a4=0,a5=0,a6=0,a7=0;
    int e = e0;
    for (; e + 4 <= e1; e += 4) {
        int c0 = __builtin_nontemporal_load(col + e);
        int c1 = __builtin_nontemporal_load(col + e + 1);
        int c2 = __builtin_nontemporal_load(col + e + 2);
        int c3 = __builtin_nontemporal_load(col + e + 3);
        float v0 = __builtin_nontemporal_load(vals + e);
        float v1 = __builtin_nontemporal_load(vals + e + 1);
        float v2 = __builtin_nontemporal_load(vals + e + 2);
        float v3 = __builtin_nontemporal_load(vals + e + 3);
        uint4 u0 = *reinterpret_cast<const uint4*>(Tb + (size_t)c0 * 48 + t * 4);
        uint4 u1 = *reinterpret_cast<const uint4*>(Tb + (size_t)c1 * 48 + t * 4);
        uint4 u2 = *reinterpret_cast<const uint4*>(Tb + (size_t)c2 * 48 + t * 4);
        uint4 u3 = *reinterpret_cast<const uint4*>(Tb + (size_t)c3 * 48 + t * 4);
        FMA8(u0, v0) FMA8(u1, v1) FMA8(u2, v2) FMA8(u3, v3)
    }
    for (; e < e1; ++e) {
        float v = __builtin_nontemporal_load(vals + e);
        int   c = __builtin_nontemporal_load(col + e);
        uint4 u = *reinterpret_cast<const uint4*>(Tb + (size_t)c * 48 + t * 4);
        FMA8(u, v)
    }
    float* hp = H + (size_t)n * GD + t * 8;
    nt_store4(hp,     fmaxf(a0,0.f), fmaxf(a1,0.f), fmaxf(a2,0.f), fmaxf(a3,0.f));
    nt_store4(hp + 4, fmaxf(a4,0.f), fmaxf(a5,0.f), fmaxf(a6,0.f), fmaxf(a7,0.f));
}

#define FMA12(U, W_, V)                                               \
    a0 += (V) * bflo((U).x); a1 += (V) * bfhi((U).x);                 \
    a2 += (V) * bflo((U).y); a3 += (V) * bfhi((U).y);                 \
    a4 += (V) * bflo((U).z); a5 += (V) * bfhi((U).z);                 \
    a6 += (V) * bflo((U).w); a7 += (V) * bfhi((U).w);                 \
    a8 += (V) * bflo((W_).x); a9 += (V) * bfhi((W_).x);               \
    a10 += (V) * bflo((W_).y); a11 += (V) * bfhi((W_).y);

// 8 threads/node; lane t owns cols [8t..8t+7] + [64+4t..64+4t+3]; shuffle l2-norm.
__global__ void spmm_relu_norm_k(const int* __restrict__ rp, const int* __restrict__ col,
                                 const float* __restrict__ vals,
                                 const unsigned* __restrict__ Tb, float* __restrict__ H) {
    int idx = blockIdx.x * blockDim.x + threadIdx.x;
    int n = idx >> 3;
    if (n >= GN) return;
    int t = idx & 7;
    int e0 = rp[n], e1 = rp[n + 1];
    float a0=0,a1=0,a2=0,a3=0,a4=0,a5=0,a6=0,a7=0,a8=0,a9=0,a10=0,a11=0;
    int e = e0;
    for (; e + 4 <= e1; e += 4) {
        int c0 = __builtin_nontemporal_load(col + e);
        int c1 = __builtin_nontemporal_load(col + e + 1);
        int c2 = __builtin_nontemporal_load(col + e + 2);
        int c3 = __builtin_nontemporal_load(col + e + 3);
        float v0 = __builtin_nontemporal_load(vals + e);
        float v1 = __builtin_nontemporal_load(vals + e + 1);
        float v2 = __builtin_nontemporal_load(vals + e + 2);
        float v3 = __builtin_nontemporal_load(vals + e + 3);
        const unsigned* r0p = Tb + (size_t)c0 * 48;
        const unsigned* r1p = Tb + (size_t)c1 * 48;
        const unsigned* r2p = Tb + (size_t)c2 * 48;
        const unsigned* r3p = Tb + (size_t)c3 * 48;
        uint4 u0 = *reinterpret_cast<const uint4*>(r0p + t * 4);
        uint2 w0 = *reinterpret_cast<const uint2*>(r0p + 32 + t * 2);
        uint4 u1 = *reinterpret_cast<const uint4*>(r1p + t * 4);
        uint2 w1 = *reinterpret_cast<const uint2*>(r1p + 32 + t * 2);
        uint4 u2 = *reinterpret_cast<const uint4*>(r2p + t * 4);
        uint2 w2 = *reinterpret_cast<const uint2*>(r2p + 32 + t * 2);
        uint4 u3 = *reinterpret_cast<const uint4*>(r3p + t * 4);
        uint2 w3 = *reinterpret_cast<const uint2*>(r3p + 32 + t * 2);
        FMA12(u0, w0, v0) FMA12(u1, w1, v1) FMA12(u2, w2, v2) FMA12(u3, w3, v3)
    }
    for (; e < e1; ++e) {
        float v = __builtin_nontemporal_load(vals + e);
        int   c = __builtin_nontemporal_load(col + e);
        const unsigned* r = Tb + (size_t)c * 48;
        uint4 u = *reinterpret_cast<const uint4*>(r + t * 4);
        uint2 w = *reinterpret_cast<const uint2*>(r + 32 + t * 2);
        FMA12(u, w, v)
    }
    a0=fmaxf(a0,0.f); a1=fmaxf(a1,0.f); a2=fmaxf(a2,0.f); a3=fmaxf(a3,0.f);
    a4=fmaxf(a4,0.f); a5=fmaxf(a5,0.f); a6=fmaxf(a6,0.f); a7=fmaxf(a7,0.f);
    a8=fmaxf(a8,0.f); a9=fmaxf(a9,0.f); a10=fmaxf(a10,0.f); a11=fmaxf(a11,0.f);
    float ss = a0*a0+a1*a1+a2*a2+a3*a3+a4*a4+a5*a5+a6*a6+a7*a7+a8*a8+a9*a9+a10*a10+a11*a11;
    ss += __shfl_xor(ss, 1);
    ss += __shfl_xor(ss, 2);
    ss += __shfl_xor(ss, 4);
    float s = rsqrtf(fmaxf(ss, L2EPS));
    a0*=s; a1*=s; a2*=s; a3*=s; a4*=s; a5*=s;
    a6*=s; a7*=s; a8*=s; a9*=s; a10*=s; a11*=s;
    float* hp = H + (size_t)n * GD;
    *reinterpret_cast<float4*>(hp + t * 8)     = make_float4(a0, a1, a2, a3);
    *reinterpret_cast<float4*>(hp + t * 8 + 4) = make_float4(a4, a5, a6, a7);
    *reinterpret_cast<float4*>(hp + 64 + t * 4) = make_float4(a8, a9, a10, a11);
}

// fused classifier + softmax: 320 threads = 32 row-quads (10 threads each, 4x4 tile),
// logits to LDS, then 1 thread per row does softmax and writes probs.
__global__ __launch_bounds__(320) void cls_sm_k(const float* __restrict__ A,
                                                const float* __restrict__ WC,
                                                const float* __restrict__ BC,
                                                float* __restrict__ PROBS) {
    __shared__ float4 w4[GD * 10];         // 15360 B
    __shared__ float lg[128][GC];          // 20480 B
    const float4* W4 = reinterpret_cast<const float4*>(WC);
    for (int i = threadIdx.x; i < GD * 10; i += 320) w4[i] = W4[i];
    __syncthreads();

    const int tid = threadIdx.x;
    const int lq = tid / 10;               // 0..31 local row-quad
    const int q  = tid - lq * 10;          // 0..9 col-quad
    const int r0 = (blockIdx.x * 32 + lq) * 4;
    if (r0 < GN) {
        const float* a = A + (size_t)r0 * GD;
        float4 acc0 = {0,0,0,0}, acc1 = {0,0,0,0}, acc2 = {0,0,0,0}, acc3 = {0,0,0,0};
        for (int k0 = 0; k0 < GD; k0 += 4) {
            float4 a0 = *reinterpret_cast<const float4*>(a + k0);
            float4 a1 = *reinterpret_cast<const float4*>(a + GD + k0);
            float4 a2 = *reinterpret_cast<const float4*>(a + 2 * GD + k0);
            float4 a3 = *reinterpret_cast<const float4*>(a + 3 * GD + k0);
#pragma unroll
            for (int kk = 0; kk < 4; ++kk) {
                float4 w = w4[(k0 + kk) * 10 + q];
                float s0 = ((const float*)&a0)[kk];
                float s1 = ((const float*)&a1)[kk];
                float s2 = ((const float*)&a2)[kk];
                float s3 = ((const float*)&a3)[kk];
                acc0.x += s0 * w.x; acc0.y += s0 * w.y; acc0.z += s0 * w.z; acc0.w += s0 * w.w;
                acc1.x += s1 * w.x; acc1.y += s1 * w.y; acc1.z += s1 * w.z; acc1.w += s1 * w.w;
                acc2.x += s2 * w.x; acc2.y += s2 * w.y; acc2.z += s2 * w.z; acc2.w += s2 * w.w;
                acc3.x += s3 * w.x; acc3.y += s3 * w.y; acc3.z += s3 * w.z; acc3.w += s3 * w.w;
            }
        }
        float4 b = *reinterpret_cast<const float4*>(BC + q * 4);
        acc0.x += b.x; acc0.y += b.y; acc0.z += b.z; acc0.w += b.w;
        acc1.x += b.x; acc1.y += b.y; acc1.z += b.z; acc1.w += b.w;
        acc2.x += b.x; acc2.y += b.y; acc2.z += b.z; acc2.w += b.w;
        acc3.x += b.x; acc3.y += b.y; acc3.z += b.z; acc3.w += b.w;
        *reinterpret_cast<float4*>(&lg[lq * 4 + 0][q * 4]) = acc0;
        *reinterpret_cast<float4*>(&lg[lq * 4 + 1][q * 4]) = acc1;
        *reinterpret_cast<float4*>(&lg[lq * 4 + 2][q * 4]) = acc2;
        *reinterpret_cast<float4*>(&lg[lq * 4 + 3][q * 4]) = acc3;
    }
    __syncthreads();

    if (tid < 128) {
        int r = blockIdx.x * 128 + tid;
        if (r < GN) {
            const float* row = lg[tid];
            float m = row[0];
#pragma unroll
            for (int c = 1; c < GC; ++c) m = fmaxf(m, row[c]);
            float ex[GC];
            float sum = 0.f;
#pragma unroll
            for (int c = 0; c < GC; ++c) { ex[c] = __expf(row[c] - m); sum += ex[c]; }
            float inv = 1.f / sum;
            float4* pr = reinterpret_cast<float4*>(PROBS + (size_t)r * GC);
#pragma unroll
            for (int i = 0; i < 10; ++i)
                pr[i] = make_float4(ex[i*4] * inv, ex[i*4+1] * inv,
                                    ex[i*4+2] * inv, ex[i*4+3] * inv);
        }
    }
}

extern "C" void kernel_launch(void* const* d_in, const int* in_sizes, int n_in,
                              void* d_out, int out_size, void* d_ws, size_t ws_size,
                              hipStream_t stream) {
    const int*   row  = (const int*)d_in[0];
    const int*   col  = (const int*)d_in[1];
    const float* vals = (const float*)d_in[2];
    const float* x    = (const float*)d_in[3];
    const float* w1   = (const float*)d_in[4];
    const float* w2   = (const float*)d_in[5];
    const float* wc   = (const float*)d_in[6];
    const float* bc   = (const float*)d_in[7];

    float* out   = (float*)d_out;                 // [N, D]
    float* probs = out + (size_t)GN * GD;         // [N, C]

    char*  ws  = (char*)d_ws;
    int*   rp  = (int*)ws;                                        // (N+1) ints
    size_t off = (((size_t)(GN + 1) * 4) + 511) & ~(size_t)511;
    unsigned* buf = (unsigned*)(ws + off);        // bf16 [N,96] (48 uints/row)
    off += (size_t)GN * GD * 4;
    off = (off + 511) & ~(size_t)511;
    unsigned* Wb1 = (unsigned*)(ws + off);        // 4608 uints MFMA B-frags of w1
    unsigned* Wb2 = Wb1 + 4608;

    // rp + W packs
    prep_k<<<(GN + 1 + 255) / 256, 256, 0, stream>>>(row, w1, w2, rp, Wb1, Wb2);
    // t1 = bf16(x @ w1)
    gemm_mfma_k<<<GN / 16, 64, 0, stream>>>(x, (const uint4*)Wb1, (unsigned short*)buf);
    // h1 = relu(A @ t1) -> d_out (f32)
    spmm_relu_k<<<(GN * 12 + 255) / 256, 256, 0, stream>>>(rp, col, vals, buf, out);
    // t2 = bf16(h1 @ w2)
    gemm_mfma_k<<<GN / 16, 64, 0, stream>>>(out, (const uint4*)Wb2, (unsigned short*)buf);
    // out = l2norm(relu(A @ t2))
    spmm_relu_norm_k<<<(GN * 8 + 255) / 256, 256, 0, stream>>>(rp, col, vals, buf, out);
    // probs = softmax(out @ wc + bc), fused
    cls_sm_k<<<(GN + 127) / 128, 320, 0, stream>>>(out, wc, bc, probs);
}

// Round 16
// 102.222 us; speedup vs baseline: 1.3444x; 1.1242x over previous
//
#include <hip/hip_runtime.h>
#include <hip/hip_bf16.h>

#define GN 50000
#define GE 800000
#define GD 96
#define GC 40
#define L2EPS 1e-12f

typedef __attribute__((ext_vector_type(8))) short short8v;   // 8 bf16 = 4 VGPR
typedef __attribute__((ext_vector_type(4))) float f32x4;

__device__ __forceinline__ unsigned f2bf(float x) {           // RNE float->bf16 bits
    union { float f; unsigned u; } v; v.f = x;
    return (v.u + 0x7fffu + ((v.u >> 16) & 1u)) >> 16;
}
__device__ __forceinline__ float bflo(unsigned u) { return __uint_as_float(u << 16); }
__device__ __forceinline__ float bfhi(unsigned u) { return __uint_as_float(u & 0xffff0000u); }

__device__ __forceinline__ int lbound(const int* __restrict__ row, int key) {
    int lo = 0, hi = GE;
    while (lo < hi) {
        int mid = (lo + hi) >> 1;
        if (row[mid] < key) lo = mid + 1; else hi = mid;
    }
    return lo;
}

// prep: rp[i]=lower_bound(row,i) ; Wb1/Wb2 = MFMA B-fragment packs of w1/w2.
__global__ void prep_k(const int* __restrict__ row, const float* __restrict__ w1,
                       const float* __restrict__ w2, int* __restrict__ rp,
                       unsigned* __restrict__ Wb1, unsigned* __restrict__ Wb2) {
    int i = blockIdx.x * blockDim.x + threadIdx.x;
    if (i <= GN) rp[i] = lbound(row, i);
    if (i < 2 * 4608) {
        const float* W = (i < 4608) ? w1 : w2;
        unsigned* Wb   = (i < 4608) ? Wb1 : Wb2;
        int j = (i < 4608) ? i : i - 4608;
        int r = j & 3;
        int lane = (j >> 2) & 63;
        int frag = j >> 8;                 // 0..17
        int nt = frag / 3, kt = frag - nt * 3;
        int c = nt * 16 + (lane & 15);
        int k = kt * 32 + (lane >> 4) * 8 + r * 2;
        Wb[j] = f2bf(W[k * GD + c]) | (f2bf(W[(k + 1) * GD + c]) << 16);
    }
}

// O_bf16[N,96] = A_f32[N,96] @ W ; MFMA 16x16x32 bf16 with split-A (hi+lo -> A exact).
__global__ __launch_bounds__(64) void gemm_mfma_k(const float* __restrict__ A,
                                                  const uint4* __restrict__ Wb,
                                                  unsigned short* __restrict__ O) {
    const int tile = blockIdx.x;            // 0..3124
    const int l  = threadIdx.x;
    const int m  = l & 15;
    const int kg = l >> 4;

    const float* arow = A + (size_t)(tile * 16 + m) * GD + kg * 8;
    short8v ah[3], al[3];
#pragma unroll
    for (int kt = 0; kt < 3; ++kt) {
        const float4* ap = reinterpret_cast<const float4*>(arow + kt * 32);
        float4 x0 = ap[0], x1 = ap[1];
        uint4 H, L;
        H.x = f2bf(x0.x) | (f2bf(x0.y) << 16);
        H.y = f2bf(x0.z) | (f2bf(x0.w) << 16);
        H.z = f2bf(x1.x) | (f2bf(x1.y) << 16);
        H.w = f2bf(x1.z) | (f2bf(x1.w) << 16);
        L.x = f2bf(x0.x - bflo(H.x)) | (f2bf(x0.y - bfhi(H.x)) << 16);
        L.y = f2bf(x0.z - bflo(H.y)) | (f2bf(x0.w - bfhi(H.y)) << 16);
        L.z = f2bf(x1.x - bflo(H.z)) | (f2bf(x1.y - bfhi(H.z)) << 16);
        L.w = f2bf(x1.z - bflo(H.w)) | (f2bf(x1.w - bfhi(H.w)) << 16);
        union { uint4 u; short8v s; } ch, cl;
        ch.u = H; cl.u = L;
        ah[kt] = ch.s; al[kt] = cl.s;
    }

#pragma unroll
    for (int nt = 0; nt < 6; ++nt) {
        f32x4 acc = {0.f, 0.f, 0.f, 0.f};
#pragma unroll
        for (int kt = 0; kt < 3; ++kt) {
            union { uint4 u; short8v s; } b;
            b.u = Wb[(nt * 3 + kt) * 64 + l];
            acc = __builtin_amdgcn_mfma_f32_16x16x32_bf16(ah[kt], b.s, acc, 0, 0, 0);
            acc = __builtin_amdgcn_mfma_f32_16x16x32_bf16(al[kt], b.s, acc, 0, 0, 0);
        }
        int ccol = nt * 16 + m;
#pragma unroll
        for (int reg = 0; reg < 4; ++reg) {
            int rrow = tile * 16 + kg * 4 + reg;
            O[(size_t)rrow * GD + ccol] = (unsigned short)f2bf(acc[reg]);
        }
    }
}

// O_bf16[N,96] = A_bf16[N,96] @ W ; A already bf16 -> exact, single MFMA per frag.
__global__ __launch_bounds__(64) void gemm_mfma_bf_k(const unsigned* __restrict__ Ab,
                                                     const uint4* __restrict__ Wb,
                                                     unsigned short* __restrict__ O) {
    const int tile = blockIdx.x;
    const int l  = threadIdx.x;
    const int m  = l & 15;
    const int kg = l >> 4;

    const unsigned* arow = Ab + (size_t)(tile * 16 + m) * 48;
    short8v af[3];
#pragma unroll
    for (int kt = 0; kt < 3; ++kt) {
        union { uint4 u; short8v s; } c;
        c.u = *reinterpret_cast<const uint4*>(arow + kt * 16 + kg * 4);
        af[kt] = c.s;
    }

#pragma unroll
    for (int nt = 0; nt < 6; ++nt) {
        f32x4 acc = {0.f, 0.f, 0.f, 0.f};
#pragma unroll
        for (int kt = 0; kt < 3; ++kt) {
            union { uint4 u; short8v s; } b;
            b.u = Wb[(nt * 3 + kt) * 64 + l];
            acc = __builtin_amdgcn_mfma_f32_16x16x32_bf16(af[kt], b.s, acc, 0, 0, 0);
        }
        int ccol = nt * 16 + m;
#pragma unroll
        for (int reg = 0; reg < 4; ++reg) {
            int rrow = tile * 16 + kg * 4 + reg;
            O[(size_t)rrow * GD + ccol] = (unsigned short)f2bf(acc[reg]);
        }
    }
}

#define FMA8(U, V)                                                    \
    a0 += (V) * bflo((U).x); a1 += (V) * bfhi((U).x);                 \
    a2 += (V) * bflo((U).y); a3 += (V) * bfhi((U).y);                 \
    a4 += (V) * bflo((U).z); a5 += (V) * bfhi((U).z);                 \
    a6 += (V) * bflo((U).w); a7 += (V) * bfhi((U).w);

// 12 threads/node; lane t gathers one uint4 (cols t*8..t*8+7) per edge; unroll-4.
// OUTPUT: bf16 (h1 feeds only GEMM-2) — halves write+read traffic vs f32.
__global__ void spmm_relu_bf_k(const int* __restrict__ rp, const int* __restrict__ col,
                               const float* __restrict__ vals,
                               const unsigned* __restrict__ Tb, unsigned* __restrict__ Hb) {
    int idx = blockIdx.x * blockDim.x + threadIdx.x;
    int n = idx / 12;
    if (n >= GN) return;
    int t = idx - n * 12;
    int e0 = rp[n], e1 = rp[n + 1];
    float a0=0,a1=0,a2=0,a3=0,a4=0,a5=0,a6=0,a7=0;
    int e = e0;
    for (; e + 4 <= e1; e += 4) {
        int c0 = col[e], c1 = col[e+1], c2 = col[e+2], c3 = col[e+3];
        float v0 = vals[e], v1 = vals[e+1], v2 = vals[e+2], v3 = vals[e+3];
        uint4 u0 = *reinterpret_cast<const uint4*>(Tb + (size_t)c0 * 48 + t * 4);
        uint4 u1 = *reinterpret_cast<const uint4*>(Tb + (size_t)c1 * 48 + t * 4);
        uint4 u2 = *reinterpret_cast<const uint4*>(Tb + (size_t)c2 * 48 + t * 4);
        uint4 u3 = *reinterpret_cast<const uint4*>(Tb + (size_t)c3 * 48 + t * 4);
        FMA8(u0, v0) FMA8(u1, v1) FMA8(u2, v2) FMA8(u3, v3)
    }
    for (; e < e1; ++e) {
        float v = vals[e];
        uint4 u = *reinterpret_cast<const uint4*>(Tb + (size_t)col[e] * 48 + t * 4);
        FMA8(u, v)
    }
    uint4 r;
    r.x = f2bf(fmaxf(a0,0.f)) | (f2bf(fmaxf(a1,0.f)) << 16);
    r.y = f2bf(fmaxf(a2,0.f)) | (f2bf(fmaxf(a3,0.f)) << 16);
    r.z = f2bf(fmaxf(a4,0.f)) | (f2bf(fmaxf(a5,0.f)) << 16);
    r.w = f2bf(fmaxf(a6,0.f)) | (f2bf(fmaxf(a7,0.f)) << 16);
    *reinterpret_cast<uint4*>(Hb + (size_t)n * 48 + t * 4) = r;
}

#define FMA12(U, W_, V)                                               \
    a0 += (V) * bflo((U).x); a1 += (V) * bfhi((U).x);                 \
    a2 += (V) * bflo((U).y); a3 += (V) * bfhi((U).y);                 \
    a4 += (V) * bflo((U).z); a5 += (V) * bfhi((U).z);                 \
    a6 += (V) * bflo((U).w); a7 += (V) * bfhi((U).w);                 \
    a8 += (V) * bflo((W_).x); a9 += (V) * bfhi((W_).x);               \
    a10 += (V) * bflo((W_).y); a11 += (V) * bfhi((W_).y);

// 8 threads/node; lane t owns cols [8t..8t+7] + [64+4t..64+4t+3]; shuffle l2-norm.
__global__ void spmm_relu_norm_k(const int* __restrict__ rp, const int* __restrict__ col,
                                 const float* __restrict__ vals,
                                 const unsigned* __restrict__ Tb, float* __restrict__ H) {
    int idx = blockIdx.x * blockDim.x + threadIdx.x;
    int n = idx >> 3;
    if (n >= GN) return;
    int t = idx & 7;
    int e0 = rp[n], e1 = rp[n + 1];
    float a0=0,a1=0,a2=0,a3=0,a4=0,a5=0,a6=0,a7=0,a8=0,a9=0,a10=0,a11=0;
    int e = e0;
    for (; e + 4 <= e1; e += 4) {
        int c0 = col[e], c1 = col[e+1], c2 = col[e+2], c3 = col[e+3];
        float v0 = vals[e], v1 = vals[e+1], v2 = vals[e+2], v3 = vals[e+3];
        const unsigned* r0p = Tb + (size_t)c0 * 48;
        const unsigned* r1p = Tb + (size_t)c1 * 48;
        const unsigned* r2p = Tb + (size_t)c2 * 48;
        const unsigned* r3p = Tb + (size_t)c3 * 48;
        uint4 u0 = *reinterpret_cast<const uint4*>(r0p + t * 4);
        uint2 w0 = *reinterpret_cast<const uint2*>(r0p + 32 + t * 2);
        uint4 u1 = *reinterpret_cast<const uint4*>(r1p + t * 4);
        uint2 w1 = *reinterpret_cast<const uint2*>(r1p + 32 + t * 2);
        uint4 u2 = *reinterpret_cast<const uint4*>(r2p + t * 4);
        uint2 w2 = *reinterpret_cast<const uint2*>(r2p + 32 + t * 2);
        uint4 u3 = *reinterpret_cast<const uint4*>(r3p + t * 4);
        uint2 w3 = *reinterpret_cast<const uint2*>(r3p + 32 + t * 2);
        FMA12(u0, w0, v0) FMA12(u1, w1, v1) FMA12(u2, w2, v2) FMA12(u3, w3, v3)
    }
    for (; e < e1; ++e) {
        float v = vals[e];
        const unsigned* r = Tb + (size_t)col[e] * 48;
        uint4 u = *reinterpret_cast<const uint4*>(r + t * 4);
        uint2 w = *reinterpret_cast<const uint2*>(r + 32 + t * 2);
        FMA12(u, w, v)
    }
    a0=fmaxf(a0,0.f); a1=fmaxf(a1,0.f); a2=fmaxf(a2,0.f); a3=fmaxf(a3,0.f);
    a4=fmaxf(a4,0.f); a5=fmaxf(a5,0.f); a6=fmaxf(a6,0.f); a7=fmaxf(a7,0.f);
    a8=fmaxf(a8,0.f); a9=fmaxf(a9,0.f); a10=fmaxf(a10,0.f); a11=fmaxf(a11,0.f);
    float ss = a0*a0+a1*a1+a2*a2+a3*a3+a4*a4+a5*a5+a6*a6+a7*a7+a8*a8+a9*a9+a10*a10+a11*a11;
    ss += __shfl_xor(ss, 1);
    ss += __shfl_xor(ss, 2);
    ss += __shfl_xor(ss, 4);
    float s = rsqrtf(fmaxf(ss, L2EPS));
    a0*=s; a1*=s; a2*=s; a3*=s; a4*=s; a5*=s;
    a6*=s; a7*=s; a8*=s; a9*=s; a10*=s; a11*=s;
    float* hp = H + (size_t)n * GD;
    *reinterpret_cast<float4*>(hp + t * 8)      = make_float4(a0, a1, a2, a3);
    *reinterpret_cast<float4*>(hp + t * 8 + 4)  = make_float4(a4, a5, a6, a7);
    *reinterpret_cast<float4*>(hp + 64 + t * 4) = make_float4(a8, a9, a10, a11);
}

// fused classifier + softmax: 320 threads = 32 row-quads (10 threads each, 4x4 tile),
// logits to LDS, then 1 thread per row does softmax and writes probs.
__global__ __launch_bounds__(320) void cls_sm_k(const float* __restrict__ A,
                                                const float* __restrict__ WC,
                                                const float* __restrict__ BC,
                                                float* __restrict__ PROBS) {
    __shared__ float4 w4[GD * 10];         // 15360 B
    __shared__ float lg[128][GC];          // 20480 B
    const float4* W4 = reinterpret_cast<const float4*>(WC);
    for (int i = threadIdx.x; i < GD * 10; i += 320) w4[i] = W4[i];
    __syncthreads();

    const int tid = threadIdx.x;
    const int lq = tid / 10;               // 0..31 local row-quad
    const int q  = tid - lq * 10;          // 0..9 col-quad
    const int r0 = (blockIdx.x * 32 + lq) * 4;
    if (r0 < GN) {
        const float* a = A + (size_t)r0 * GD;
        float4 acc0 = {0,0,0,0}, acc1 = {0,0,0,0}, acc2 = {0,0,0,0}, acc3 = {0,0,0,0};
        for (int k0 = 0; k0 < GD; k0 += 4) {
            float4 a0 = *reinterpret_cast<const float4*>(a + k0);
            float4 a1 = *reinterpret_cast<const float4*>(a + GD + k0);
            float4 a2 = *reinterpret_cast<const float4*>(a + 2 * GD + k0);
            float4 a3 = *reinterpret_cast<const float4*>(a + 3 * GD + k0);
#pragma unroll
            for (int kk = 0; kk < 4; ++kk) {
                float4 w = w4[(k0 + kk) * 10 + q];
                float s0 = ((const float*)&a0)[kk];
                float s1 = ((const float*)&a1)[kk];
                float s2 = ((const float*)&a2)[kk];
                float s3 = ((const float*)&a3)[kk];
                acc0.x += s0 * w.x; acc0.y += s0 * w.y; acc0.z += s0 * w.z; acc0.w += s0 * w.w;
                acc1.x += s1 * w.x; acc1.y += s1 * w.y; acc1.z += s1 * w.z; acc1.w += s1 * w.w;
                acc2.x += s2 * w.x; acc2.y += s2 * w.y; acc2.z += s2 * w.z; acc2.w += s2 * w.w;
                acc3.x += s3 * w.x; acc3.y += s3 * w.y; acc3.z += s3 * w.z; acc3.w += s3 * w.w;
            }
        }
        float4 b = *reinterpret_cast<const float4*>(BC + q * 4);
        acc0.x += b.x; acc0.y += b.y; acc0.z += b.z; acc0.w += b.w;
        acc1.x += b.x; acc1.y += b.y; acc1.z += b.z; acc1.w += b.w;
        acc2.x += b.x; acc2.y += b.y; acc2.z += b.z; acc2.w += b.w;
        acc3.x += b.x; acc3.y += b.y; acc3.z += b.z; acc3.w += b.w;
        *reinterpret_cast<float4*>(&lg[lq * 4 + 0][q * 4]) = acc0;
        *reinterpret_cast<float4*>(&lg[lq * 4 + 1][q * 4]) = acc1;
        *reinterpret_cast<float4*>(&lg[lq * 4 + 2][q * 4]) = acc2;
        *reinterpret_cast<float4*>(&lg[lq * 4 + 3][q * 4]) = acc3;
    }
    __syncthreads();

    if (tid < 128) {
        int r = blockIdx.x * 128 + tid;
        if (r < GN) {
            const float* row = lg[tid];
            float m = row[0];
#pragma unroll
            for (int c = 1; c < GC; ++c) m = fmaxf(m, row[c]);
            float ex[GC];
            float sum = 0.f;
#pragma unroll
            for (int c = 0; c < GC; ++c) { ex[c] = __expf(row[c] - m); sum += ex[c]; }
            float inv = 1.f / sum;
            float4* pr = reinterpret_cast<float4*>(PROBS + (size_t)r * GC);
#pragma unroll
            for (int i = 0; i < 10; ++i)
                pr[i] = make_float4(ex[i*4] * inv, ex[i*4+1] * inv,
                                    ex[i*4+2] * inv, ex[i*4+3] * inv);
        }
    }
}

extern "C" void kernel_launch(void* const* d_in, const int* in_sizes, int n_in,
                              void* d_out, int out_size, void* d_ws, size_t ws_size,
                              hipStream_t stream) {
    const int*   row  = (const int*)d_in[0];
    const int*   col  = (const int*)d_in[1];
    const float* vals = (const float*)d_in[2];
    const float* x    = (const float*)d_in[3];
    const float* w1   = (const float*)d_in[4];
    const float* w2   = (const float*)d_in[5];
    const float* wc   = (const float*)d_in[6];
    const float* bc   = (const float*)d_in[7];

    float* out   = (float*)d_out;                 // [N, D]
    float* probs = out + (size_t)GN * GD;         // [N, C]

    char*  ws  = (char*)d_ws;
    int*   rp  = (int*)ws;                                        // (N+1) ints
    size_t off = (((size_t)(GN + 1) * 4) + 511) & ~(size_t)511;
    unsigned* buf = (unsigned*)(ws + off);        // bf16 t-table [N,96] (48 uints/row)
    off += (size_t)GN * 48 * 4;
    off = (off + 511) & ~(size_t)511;
    unsigned* hb  = (unsigned*)(ws + off);        // bf16 h1 [N,96] (48 uints/row)
    off += (size_t)GN * 48 * 4;
    off = (off + 511) & ~(size_t)511;
    unsigned* Wb1 = (unsigned*)(ws + off);        // 4608 uints MFMA B-frags of w1
    unsigned* Wb2 = Wb1 + 4608;

    // rp + W packs
    prep_k<<<(GN + 1 + 255) / 256, 256, 0, stream>>>(row, w1, w2, rp, Wb1, Wb2);
    // t1 = bf16(x @ w1)
    gemm_mfma_k<<<GN / 16, 64, 0, stream>>>(x, (const uint4*)Wb1, (unsigned short*)buf);
    // h1 = bf16(relu(A @ t1)) -> hb
    spmm_relu_bf_k<<<(GN * 12 + 255) / 256, 256, 0, stream>>>(rp, col, vals, buf, hb);
    // t2 = bf16(h1 @ w2)  [bf16-in GEMM, 18 MFMAs]
    gemm_mfma_bf_k<<<GN / 16, 64, 0, stream>>>(hb, (const uint4*)Wb2, (unsigned short*)buf);
    // out = l2norm(relu(A @ t2))
    spmm_relu_norm_k<<<(GN * 8 + 255) / 256, 256, 0, stream>>>(rp, col, vals, buf, out);
    // probs = softmax(out @ wc + bc), fused
    cls_sm_k<<<(GN + 127) / 128, 320, 0, stream>>>(out, wc, bc, probs);
}